// Round 1
// baseline (1613.106 us; speedup 1.0000x reference)
//
#include <hip/hip_runtime.h>

#define BB 2
#define SS 2048
#define EE 1024
#define HH 16
#define DD_ 64
#define NQKV (3*EE)
#define MROWS (BB*SS)

// ---------------------------------------------------------------------------
// QKV GEMM: C[m,n] = sum_k x[m,k]*qkv_w[n,k] + qkv_b[n], masked by head gate,
// scattered to q/k/v in [B,H,S,D] layout.
// ---------------------------------------------------------------------------
__global__ __launch_bounds__(256) void qkv_gemm_kernel(
    const float* __restrict__ x, const float* __restrict__ w,
    const float* __restrict__ bias, const float* __restrict__ gates,
    const float* __restrict__ imp, const float* __restrict__ thr,
    float* __restrict__ qout, float* __restrict__ kout, float* __restrict__ vout)
{
    __shared__ float As[64][17];
    __shared__ float Bs[64][17];
    const int tid = threadIdx.x;
    const int tx = tid & 15, ty = tid >> 4;
    const int m0 = blockIdx.y << 6;
    const int n0 = blockIdx.x << 6;
    const int lr = tid >> 2, lc = (tid & 3) << 2;

    const float* aptr = x + (size_t)(m0 + lr) * EE + lc;
    const float* bptr = w + (size_t)(n0 + lr) * EE + lc;

    float acc[4][4] = {};
    for (int k0 = 0; k0 < EE; k0 += 16) {
        float4 av = *(const float4*)(aptr + k0);
        float4 bv = *(const float4*)(bptr + k0);
        __syncthreads();
        As[lr][lc+0]=av.x; As[lr][lc+1]=av.y; As[lr][lc+2]=av.z; As[lr][lc+3]=av.w;
        Bs[lr][lc+0]=bv.x; Bs[lr][lc+1]=bv.y; Bs[lr][lc+2]=bv.z; Bs[lr][lc+3]=bv.w;
        __syncthreads();
#pragma unroll
        for (int kk = 0; kk < 16; ++kk) {
            float a[4], b[4];
#pragma unroll
            for (int i = 0; i < 4; ++i) a[i] = As[ty*4+i][kk];
#pragma unroll
            for (int j = 0; j < 4; ++j) b[j] = Bs[tx*4+j][kk];
#pragma unroll
            for (int i = 0; i < 4; ++i)
#pragma unroll
                for (int j = 0; j < 4; ++j)
                    acc[i][j] += a[i]*b[j];
        }
    }

    // n0 is a multiple of 64 and head span is 64 -> which/head uniform per block
    const int which = n0 >> 10;          // 0:q 1:k 2:v
    const int e0 = n0 & 1023;
    const int h = e0 >> 6;
    const float gs = 1.f / (1.f + __expf(-gates[h] * imp[h]));
    const float maskv = (gs > thr[0]) ? 1.f : 0.f;
    float* __restrict__ dst = (which == 0) ? qout : ((which == 1) ? kout : vout);
    const int d0 = tx << 2;
#pragma unroll
    for (int i = 0; i < 4; ++i) {
        const int m = m0 + ty*4 + i;
        const int b = m >> 11;           // / SS
        const int s = m & (SS - 1);
        float4 o;
        o.x = (acc[i][0] + bias[n0 + d0 + 0]) * maskv;
        o.y = (acc[i][1] + bias[n0 + d0 + 1]) * maskv;
        o.z = (acc[i][2] + bias[n0 + d0 + 2]) * maskv;
        o.w = (acc[i][3] + bias[n0 + d0 + 3]) * maskv;
        *(float4*)(dst + ((size_t)(b*HH + h) * SS + s) * DD_ + d0) = o;
    }
}

// ---------------------------------------------------------------------------
// Output GEMM: y[m,n] = sum_k a[m,k]*out_w[n,k] + out_b[n]
// ---------------------------------------------------------------------------
__global__ __launch_bounds__(256) void out_gemm_kernel(
    const float* __restrict__ a, const float* __restrict__ w,
    const float* __restrict__ bias, float* __restrict__ y)
{
    __shared__ float As[64][17];
    __shared__ float Bs[64][17];
    const int tid = threadIdx.x;
    const int tx = tid & 15, ty = tid >> 4;
    const int m0 = blockIdx.y << 6;
    const int n0 = blockIdx.x << 6;
    const int lr = tid >> 2, lc = (tid & 3) << 2;

    const float* aptr = a + (size_t)(m0 + lr) * EE + lc;
    const float* bptr = w + (size_t)(n0 + lr) * EE + lc;

    float acc[4][4] = {};
    for (int k0 = 0; k0 < EE; k0 += 16) {
        float4 av = *(const float4*)(aptr + k0);
        float4 bv = *(const float4*)(bptr + k0);
        __syncthreads();
        As[lr][lc+0]=av.x; As[lr][lc+1]=av.y; As[lr][lc+2]=av.z; As[lr][lc+3]=av.w;
        Bs[lr][lc+0]=bv.x; Bs[lr][lc+1]=bv.y; Bs[lr][lc+2]=bv.z; Bs[lr][lc+3]=bv.w;
        __syncthreads();
#pragma unroll
        for (int kk = 0; kk < 16; ++kk) {
            float av4[4], bv4[4];
#pragma unroll
            for (int i = 0; i < 4; ++i) av4[i] = As[ty*4+i][kk];
#pragma unroll
            for (int j = 0; j < 4; ++j) bv4[j] = Bs[tx*4+j][kk];
#pragma unroll
            for (int i = 0; i < 4; ++i)
#pragma unroll
                for (int j = 0; j < 4; ++j)
                    acc[i][j] += av4[i]*bv4[j];
        }
    }
    const int d0 = tx << 2;
#pragma unroll
    for (int i = 0; i < 4; ++i) {
        const int m = m0 + ty*4 + i;
        float4 o;
        o.x = acc[i][0] + bias[n0 + d0 + 0];
        o.y = acc[i][1] + bias[n0 + d0 + 1];
        o.z = acc[i][2] + bias[n0 + d0 + 2];
        o.w = acc[i][3] + bias[n0 + d0 + 3];
        *(float4*)(y + (size_t)m * EE + n0 + d0) = o;
    }
}

// ---------------------------------------------------------------------------
// v mean over sequence per (b,h,d)
// ---------------------------------------------------------------------------
__global__ __launch_bounds__(256) void vmean_kernel(
    const float* __restrict__ v, float* __restrict__ vm)
{
    __shared__ float red[4][64];
    const int bh = blockIdx.x;
    const int d = threadIdx.x & 63;
    const int c = threadIdx.x >> 6;  // 0..3
    const float* vp = v + (size_t)bh * SS * DD_ + (size_t)c * (SS/4) * DD_ + d;
    float s = 0.f;
    for (int t = 0; t < SS/4; ++t) s += vp[(size_t)t * DD_];
    red[c][d] = s;
    __syncthreads();
    if (c == 0)
        vm[bh*DD_ + d] = (red[0][d] + red[1][d] + red[2][d] + red[3][d]) * (1.f/SS);
}

// ---------------------------------------------------------------------------
// Flash attention (no scale, per reference): one block per (64 q rows, b*h).
// Online softmax; P kept in registers, moved via shuffles for PV.
// Epilogue adds vmean and writes [B,S,E] layout.
// ---------------------------------------------------------------------------
__global__ __launch_bounds__(256) void attn_kernel(
    const float* __restrict__ q, const float* __restrict__ k,
    const float* __restrict__ v, const float* __restrict__ vmean,
    float* __restrict__ out)
{
    __shared__ float Qs[64][65];
    __shared__ float Ks[64][65];
    __shared__ float Vs[64][65];
    const int tid = threadIdx.x;
    const int tx = tid & 15, ty = tid >> 4;
    const int lane = tid & 63;
    const int bh = blockIdx.y;
    const int q0 = blockIdx.x << 6;
    const size_t base = (size_t)bh * SS * DD_;
    const float* qb = q + base;
    const float* kb = k + base;
    const float* vb = v + base;

    const int lr = tid >> 2;         // 0..63
    const int lc = (tid & 3) << 4;   // 0,16,32,48
    {
        const float* src = qb + (size_t)(q0 + lr) * DD_ + lc;
#pragma unroll
        for (int u = 0; u < 4; ++u) {
            float4 t4 = *(const float4*)(src + u*4);
            Qs[lr][lc+u*4+0]=t4.x; Qs[lr][lc+u*4+1]=t4.y;
            Qs[lr][lc+u*4+2]=t4.z; Qs[lr][lc+u*4+3]=t4.w;
        }
    }

    float accO[4][4] = {};
    float mrow[4], lrow[4];
#pragma unroll
    for (int i = 0; i < 4; ++i) { mrow[i] = -3.0e38f; lrow[i] = 0.f; }

    for (int j0 = 0; j0 < SS; j0 += 64) {
        __syncthreads();   // protect Ks/Vs from previous iteration readers
        {
            const float* ksrc = kb + (size_t)(j0 + lr) * DD_ + lc;
            const float* vsrc = vb + (size_t)(j0 + lr) * DD_ + lc;
#pragma unroll
            for (int u = 0; u < 4; ++u) {
                float4 t4 = *(const float4*)(ksrc + u*4);
                Ks[lr][lc+u*4+0]=t4.x; Ks[lr][lc+u*4+1]=t4.y;
                Ks[lr][lc+u*4+2]=t4.z; Ks[lr][lc+u*4+3]=t4.w;
                float4 s4 = *(const float4*)(vsrc + u*4);
                Vs[lr][lc+u*4+0]=s4.x; Vs[lr][lc+u*4+1]=s4.y;
                Vs[lr][lc+u*4+2]=s4.z; Vs[lr][lc+u*4+3]=s4.w;
            }
        }
        __syncthreads();

        // scores: 4x4 microtile, rows ty*4+i, cols tx*4+j
        float accS[4][4] = {};
#pragma unroll 8
        for (int dd = 0; dd < DD_; ++dd) {
            float qv[4], kv[4];
#pragma unroll
            for (int i = 0; i < 4; ++i) qv[i] = Qs[ty*4+i][dd];
#pragma unroll
            for (int j = 0; j < 4; ++j) kv[j] = Ks[tx*4+j][dd];
#pragma unroll
            for (int i = 0; i < 4; ++i)
#pragma unroll
                for (int j = 0; j < 4; ++j)
                    accS[i][j] += qv[i]*kv[j];
        }

        // online softmax per row (16 lanes share a row: same ty, tx=0..15)
#pragma unroll
        for (int i = 0; i < 4; ++i) {
            float mx = fmaxf(fmaxf(accS[i][0], accS[i][1]), fmaxf(accS[i][2], accS[i][3]));
            mx = fmaxf(mx, __shfl_xor(mx, 1, 64));
            mx = fmaxf(mx, __shfl_xor(mx, 2, 64));
            mx = fmaxf(mx, __shfl_xor(mx, 4, 64));
            mx = fmaxf(mx, __shfl_xor(mx, 8, 64));
            float mnew = fmaxf(mrow[i], mx);
            float ps = 0.f;
#pragma unroll
            for (int j = 0; j < 4; ++j) { accS[i][j] = __expf(accS[i][j] - mnew); ps += accS[i][j]; }
            ps += __shfl_xor(ps, 1, 64);
            ps += __shfl_xor(ps, 2, 64);
            ps += __shfl_xor(ps, 4, 64);
            ps += __shfl_xor(ps, 8, 64);
            float alpha = __expf(mrow[i] - mnew);
            lrow[i] = lrow[i]*alpha + ps;
            mrow[i] = mnew;
#pragma unroll
            for (int j = 0; j < 4; ++j) accO[i][j] *= alpha;
        }

        // PV: P[r][c] lives in accS of thread (same ty, tx=c>>2), reg c&3.
        for (int c0 = 0; c0 < 64; c0 += 4) {
            const int srcl = (lane & 48) + (c0 >> 2);
#pragma unroll
            for (int u = 0; u < 4; ++u) {
                float vv[4];
#pragma unroll
                for (int j = 0; j < 4; ++j) vv[j] = Vs[c0+u][tx*4+j];
#pragma unroll
                for (int i = 0; i < 4; ++i) {
                    float pvv = __shfl(accS[i][u], srcl, 64);
#pragma unroll
                    for (int j = 0; j < 4; ++j)
                        accO[i][j] += pvv * vv[j];
                }
            }
        }
    }

    // epilogue: /l, +vmean, write [B,S,E]
    const int b = bh >> 4, h = bh & (HH - 1);
    const int d0 = tx << 2;
#pragma unroll
    for (int i = 0; i < 4; ++i) {
        const int r = q0 + ty*4 + i;
        const float inv = 1.f / lrow[i];
        float4 o;
        o.x = accO[i][0]*inv + vmean[bh*DD_ + d0 + 0];
        o.y = accO[i][1]*inv + vmean[bh*DD_ + d0 + 1];
        o.z = accO[i][2]*inv + vmean[bh*DD_ + d0 + 2];
        o.w = accO[i][3]*inv + vmean[bh*DD_ + d0 + 3];
        *(float4*)(out + ((size_t)(b*SS + r)) * EE + h*DD_ + d0) = o;
    }
}

// ---------------------------------------------------------------------------
extern "C" void kernel_launch(void* const* d_in, const int* in_sizes, int n_in,
                              void* d_out, int out_size, void* d_ws, size_t ws_size,
                              hipStream_t stream)
{
    const float* x      = (const float*)d_in[0];
    const float* qkv_w  = (const float*)d_in[1];
    const float* qkv_b  = (const float*)d_in[2];
    const float* out_w  = (const float*)d_in[3];
    const float* out_b  = (const float*)d_in[4];
    const float* gates  = (const float*)d_in[5];
    const float* imp    = (const float*)d_in[6];
    const float* thr    = (const float*)d_in[7];
    float* out = (float*)d_out;

    float* ws = (float*)d_ws;
    const size_t TSZ = (size_t)BB*HH*SS*DD_;   // 4 Mi elements
    float* qbuf  = ws;
    float* kbuf  = qbuf + TSZ;
    float* vbuf  = kbuf + TSZ;
    float* vmean = vbuf + TSZ;
    float* attno = vmean + (size_t)BB*HH*DD_;

    dim3 g1(NQKV/64, MROWS/64);   // 48 x 64
    qkv_gemm_kernel<<<g1, 256, 0, stream>>>(x, qkv_w, qkv_b, gates, imp, thr,
                                            qbuf, kbuf, vbuf);
    vmean_kernel<<<BB*HH, 256, 0, stream>>>(vbuf, vmean);
    dim3 g2(SS/64, BB*HH);        // 32 x 32
    attn_kernel<<<g2, 256, 0, stream>>>(qbuf, kbuf, vbuf, vmean, attno);
    dim3 g3(EE/64, MROWS/64);     // 16 x 64
    out_gemm_kernel<<<g3, 256, 0, stream>>>(attno, out_w, out_b, out);
}

// Round 2
// 269.970 us; speedup vs baseline: 5.9751x; 5.9751x over previous
//
#include <hip/hip_runtime.h>

#define BB 2
#define SS 2048
#define EE 1024
#define HH 16
#define DD_ 64
#define BH (BB*HH)
#define NQKV (3*EE)
#define MROWS (BB*SS)

typedef _Float16 f16;
typedef _Float16 f16x8 __attribute__((ext_vector_type(8)));
typedef _Float16 f16x4 __attribute__((ext_vector_type(4)));
typedef float f32x4 __attribute__((ext_vector_type(4)));

#define MFMA16(a,b,c) __builtin_amdgcn_mfma_f32_16x16x32_f16(a,b,c,0,0,0)

// ---------------------------------------------------------------------------
// QKV GEMM, f16 MFMA: C[m,n] = sum_k x[m,k]*w[n,k] + b[n], head-masked,
// scattered as f16 to q/k/v in [B,H,S,D].
// Tile 128x128, BK=64, 256 thr = 4 waves, each wave a 64x64 quadrant
// (4x4 grid of 16x16x32 MFMA tiles).
// ---------------------------------------------------------------------------
__global__ __launch_bounds__(256) void qkv_gemm_kernel(
    const float* __restrict__ x, const float* __restrict__ w,
    const float* __restrict__ bias, const float* __restrict__ gates,
    const float* __restrict__ imp, const float* __restrict__ thr,
    f16* __restrict__ q16, f16* __restrict__ k16, f16* __restrict__ v16)
{
    __shared__ f16 As[128][72];   // +8 halfs pad, rows 16B-aligned
    __shared__ f16 Bs[128][72];
    const int tid  = threadIdx.x;
    const int wave = tid >> 6, lane = tid & 63;
    const int quad = lane >> 4, l15 = lane & 15;
    const int wm = wave & 1, wn = wave >> 1;
    const int m0 = blockIdx.y << 7, n0 = blockIdx.x << 7;

    f32x4 acc[4][4];
#pragma unroll
    for (int i = 0; i < 4; ++i)
#pragma unroll
        for (int j = 0; j < 4; ++j) acc[i][j] = (f32x4){0.f,0.f,0.f,0.f};

    for (int k0 = 0; k0 < EE; k0 += 64) {
        __syncthreads();  // guard LDS overwrite vs previous-iter frag reads
#pragma unroll
        for (int u = 0; u < 8; ++u) {
            const int f = tid + (u << 8);
            const int r = f >> 4, c4 = (f & 15) << 2;
            float4 av = *(const float4*)(x + (size_t)(m0 + r) * EE + k0 + c4);
            float4 bv = *(const float4*)(w + (size_t)(n0 + r) * EE + k0 + c4);
            f16x4 ah = { (f16)av.x, (f16)av.y, (f16)av.z, (f16)av.w };
            f16x4 bh = { (f16)bv.x, (f16)bv.y, (f16)bv.z, (f16)bv.w };
            *(f16x4*)&As[r][c4] = ah;
            *(f16x4*)&Bs[r][c4] = bh;
        }
        __syncthreads();
#pragma unroll
        for (int ks = 0; ks < 2; ++ks) {
            f16x8 af[4], bf[4];
#pragma unroll
            for (int i = 0; i < 4; ++i)
                af[i] = *(const f16x8*)&As[wm*64 + i*16 + l15][ks*32 + quad*8];
#pragma unroll
            for (int j = 0; j < 4; ++j)
                bf[j] = *(const f16x8*)&Bs[wn*64 + j*16 + l15][ks*32 + quad*8];
#pragma unroll
            for (int i = 0; i < 4; ++i)
#pragma unroll
                for (int j = 0; j < 4; ++j)
                    acc[i][j] = MFMA16(af[i], bf[j], acc[i][j]);
        }
    }

    // epilogue: wave covers 64 cols = exactly one head of one of q/k/v
    const int nb    = n0 + wn * 64;
    const int which = nb >> 10;
    const int h     = (nb & 1023) >> 6;
    const float gs   = 1.f / (1.f + __expf(-gates[h] * imp[h]));
    const float mask = (gs > thr[0]) ? 1.f : 0.f;
    f16* __restrict__ dst = (which == 0) ? q16 : ((which == 1) ? k16 : v16);
    float bv[4];
#pragma unroll
    for (int j = 0; j < 4; ++j) bv[j] = bias[nb + j*16 + l15];
#pragma unroll
    for (int i = 0; i < 4; ++i) {
#pragma unroll
        for (int reg = 0; reg < 4; ++reg) {
            const int m = m0 + wm*64 + i*16 + quad*4 + reg;   // C/D row = quad*4+reg
            const int b = m >> 11, s = m & (SS - 1);
            f16* rowp = dst + (((size_t)(b*HH + h))*SS + s)*DD_ + l15;
#pragma unroll
            for (int j = 0; j < 4; ++j)
                rowp[j*16] = (f16)((acc[i][j][reg] + bv[j]) * mask);
        }
    }
}

// ---------------------------------------------------------------------------
// v transpose [B,H,S,D] -> [B,H,D,S] f16, + vmean (fp32, atomic partial sums)
// ---------------------------------------------------------------------------
__global__ __launch_bounds__(256) void vtrans_kernel(
    const f16* __restrict__ v16, f16* __restrict__ vt, float* __restrict__ vmean)
{
    __shared__ f16 T[64][72];
    const int tid = threadIdx.x;
    const int bh = blockIdx.y, s0 = blockIdx.x << 6;
#pragma unroll
    for (int u = 0; u < 2; ++u) {
        const int f = tid + (u << 8);
        const int r = f >> 3, c = (f & 7) << 3;
        *(float4*)&T[r][c] = *(const float4*)(v16 + ((size_t)bh*SS + s0 + r)*DD_ + c);
    }
    __syncthreads();
    const int d = tid >> 2, ch = (tid & 3) << 4;
    union { f16 h[16]; float4 f4[2]; } t;
    float ps = 0.f;
#pragma unroll
    for (int u = 0; u < 16; ++u) { f16 val = T[ch + u][d]; t.h[u] = val; ps += (float)val; }
    f16* dp = vt + ((size_t)bh*DD_ + d)*SS + s0 + ch;
    *(float4*)(dp)     = t.f4[0];
    *(float4*)(dp + 8) = t.f4[1];
    ps += __shfl_xor(ps, 1, 64);
    ps += __shfl_xor(ps, 2, 64);
    if ((tid & 3) == 0) atomicAdd(vmean + bh*DD_ + d, ps * (1.f / SS));
}

// ---------------------------------------------------------------------------
// Flash attention, f16 MFMA. One block = 64 q-rows x one (b,h).
// Computes S^T = K * Q^T so each lane owns one q-row (softmax: 2+2 shuffles).
// P^T -> LDS -> A-operand layout; PV uses V^T [D,S] tiles (contiguous frags).
// ---------------------------------------------------------------------------
__global__ __launch_bounds__(256) void attn_kernel(
    const f16* __restrict__ q16, const f16* __restrict__ k16,
    const f16* __restrict__ vt, const float* __restrict__ vmean,
    f16* __restrict__ aout)
{
    __shared__ f16 Ks[64][72];
    __shared__ f16 Vs[64][72];       // Vs[d][s]
    __shared__ f16 Ps[4][16][72];    // per-wave P round-trip buffer
    const int tid  = threadIdx.x;
    const int wave = tid >> 6, lane = tid & 63;
    const int quad = lane >> 4, l15 = lane & 15;
    const int bh = blockIdx.y, q0 = blockIdx.x << 6;
    const f16* qb = q16 + (size_t)bh * SS * DD_;
    const f16* kb = k16 + (size_t)bh * SS * DD_;
    const f16* vb = vt  + (size_t)bh * DD_ * SS;

    // Q fragments (B-operand for S^T): lane holds Q[qrow=l15][k=quad*8+j]
    f16x8 qf[2];
#pragma unroll
    for (int ks = 0; ks < 2; ++ks)
        qf[ks] = *(const f16x8*)(qb + (size_t)(q0 + wave*16 + l15)*DD_ + ks*32 + quad*8);

    f32x4 accO[4];
#pragma unroll
    for (int dt = 0; dt < 4; ++dt) accO[dt] = (f32x4){0.f,0.f,0.f,0.f};
    float mold = -3.0e38f, lsum = 0.f;   // state for q-row l15 (dup across quads)

    for (int kt = 0; kt < SS; kt += 64) {
        __syncthreads();
#pragma unroll
        for (int u = 0; u < 2; ++u) {
            const int f = tid + (u << 8);
            const int r = f >> 3, c = (f & 7) << 3;
            *(float4*)&Ks[r][c] = *(const float4*)(kb + (size_t)(kt + r)*DD_ + c);
            *(float4*)&Vs[r][c] = *(const float4*)(vb + (size_t)r*SS + kt + c);
        }
        __syncthreads();

        // S^T[key][qrow]: A = K (m=key), B = Q^T (n=qrow)
        f32x4 accS[4];
#pragma unroll
        for (int mt = 0; mt < 4; ++mt) accS[mt] = (f32x4){0.f,0.f,0.f,0.f};
#pragma unroll
        for (int ks = 0; ks < 2; ++ks)
#pragma unroll
            for (int mt = 0; mt < 4; ++mt) {
                f16x8 kf = *(const f16x8*)&Ks[mt*16 + l15][ks*32 + quad*8];
                accS[mt] = MFMA16(kf, qf[ks], accS[mt]);
            }

        // online softmax for row l15: lane holds 16 of its 64 key-scores
        float mx = -3.0e38f;
#pragma unroll
        for (int mt = 0; mt < 4; ++mt)
#pragma unroll
            for (int reg = 0; reg < 4; ++reg) mx = fmaxf(mx, accS[mt][reg]);
        mx = fmaxf(mx, __shfl_xor(mx, 16, 64));
        mx = fmaxf(mx, __shfl_xor(mx, 32, 64));
        const float mnew = fmaxf(mold, mx);
        float sum = 0.f;
#pragma unroll
        for (int mt = 0; mt < 4; ++mt)
#pragma unroll
            for (int reg = 0; reg < 4; ++reg) {
                float p = __expf(accS[mt][reg] - mnew);
                accS[mt][reg] = p; sum += p;
            }
        sum += __shfl_xor(sum, 16, 64);
        sum += __shfl_xor(sum, 32, 64);
        const float alpha = __expf(mold - mnew);
        lsum = lsum * alpha + sum;
        mold = mnew;
        // rescale accO rows (row = quad*4+reg; alpha for row r lives at lane r)
#pragma unroll
        for (int reg = 0; reg < 4; ++reg) {
            const float ar = __shfl(alpha, quad*4 + reg, 64);
#pragma unroll
            for (int dt = 0; dt < 4; ++dt) accO[dt][reg] *= ar;
        }
        // P^T -> Ps[wave][qrow=l15][key]
#pragma unroll
        for (int mt = 0; mt < 4; ++mt)
#pragma unroll
            for (int reg = 0; reg < 4; ++reg)
                Ps[wave][l15][mt*16 + quad*4 + reg] = (f16)accS[mt][reg];
        // PV: O[qrow][dim] += P * V   (in-wave LDS RAW, no barrier needed)
        f16x8 af[2];
#pragma unroll
        for (int ks = 0; ks < 2; ++ks)
            af[ks] = *(const f16x8*)&Ps[wave][l15][ks*32 + quad*8];
#pragma unroll
        for (int ks = 0; ks < 2; ++ks)
#pragma unroll
            for (int dt = 0; dt < 4; ++dt) {
                f16x8 vf = *(const f16x8*)&Vs[dt*16 + l15][ks*32 + quad*8];
                accO[dt] = MFMA16(af[ks], vf, accO[dt]);
            }
    }

    const int b = bh >> 4, h = bh & (HH - 1);
#pragma unroll
    for (int reg = 0; reg < 4; ++reg) {
        const float lf = __shfl(lsum, quad*4 + reg, 64);
        const float inv = 1.f / lf;
        const int s = q0 + wave*16 + quad*4 + reg;
#pragma unroll
        for (int dt = 0; dt < 4; ++dt) {
            float val = accO[dt][reg] * inv + vmean[bh*DD_ + dt*16 + l15];
            aout[((size_t)(b*SS + s))*EE + h*DD_ + dt*16 + l15] = (f16)val;
        }
    }
}

// ---------------------------------------------------------------------------
// Output GEMM, f16 MFMA: y[m,n] = sum_k a16[m,k]*w[n,k] + b[n]  (y fp32)
// ---------------------------------------------------------------------------
__global__ __launch_bounds__(256) void out_gemm_kernel(
    const f16* __restrict__ a, const float* __restrict__ w,
    const float* __restrict__ bias, float* __restrict__ y)
{
    __shared__ f16 As[128][72];
    __shared__ f16 Bs[128][72];
    const int tid  = threadIdx.x;
    const int wave = tid >> 6, lane = tid & 63;
    const int quad = lane >> 4, l15 = lane & 15;
    const int wm = wave & 1, wn = wave >> 1;
    const int m0 = blockIdx.y << 7, n0 = blockIdx.x << 7;

    f32x4 acc[4][4];
#pragma unroll
    for (int i = 0; i < 4; ++i)
#pragma unroll
        for (int j = 0; j < 4; ++j) acc[i][j] = (f32x4){0.f,0.f,0.f,0.f};

    for (int k0 = 0; k0 < EE; k0 += 64) {
        __syncthreads();
#pragma unroll
        for (int u = 0; u < 4; ++u) {        // A: f16 direct copy
            const int f = tid + (u << 8);
            const int r = f >> 3, c = (f & 7) << 3;
            *(float4*)&As[r][c] = *(const float4*)(a + (size_t)(m0 + r)*EE + k0 + c);
        }
#pragma unroll
        for (int u = 0; u < 8; ++u) {        // B: fp32 -> f16 convert
            const int f = tid + (u << 8);
            const int r = f >> 4, c4 = (f & 15) << 2;
            float4 bv = *(const float4*)(w + (size_t)(n0 + r)*EE + k0 + c4);
            f16x4 bh = { (f16)bv.x, (f16)bv.y, (f16)bv.z, (f16)bv.w };
            *(f16x4*)&Bs[r][c4] = bh;
        }
        __syncthreads();
#pragma unroll
        for (int ks = 0; ks < 2; ++ks) {
            f16x8 af[4], bf[4];
#pragma unroll
            for (int i = 0; i < 4; ++i)
                af[i] = *(const f16x8*)&As[wm*64 + i*16 + l15][ks*32 + quad*8];
#pragma unroll
            for (int j = 0; j < 4; ++j)
                bf[j] = *(const f16x8*)&Bs[wn*64 + j*16 + l15][ks*32 + quad*8];
#pragma unroll
            for (int i = 0; i < 4; ++i)
#pragma unroll
                for (int j = 0; j < 4; ++j)
                    acc[i][j] = MFMA16(af[i], bf[j], acc[i][j]);
        }
    }

    float bv[4];
#pragma unroll
    for (int j = 0; j < 4; ++j) bv[j] = bias[n0 + wn*64 + j*16 + l15];
#pragma unroll
    for (int i = 0; i < 4; ++i) {
#pragma unroll
        for (int reg = 0; reg < 4; ++reg) {
            const int m = m0 + wm*64 + i*16 + quad*4 + reg;
#pragma unroll
            for (int j = 0; j < 4; ++j)
                y[(size_t)m*EE + n0 + wn*64 + j*16 + l15] = acc[i][j][reg] + bv[j];
        }
    }
}

// ---------------------------------------------------------------------------
extern "C" void kernel_launch(void* const* d_in, const int* in_sizes, int n_in,
                              void* d_out, int out_size, void* d_ws, size_t ws_size,
                              hipStream_t stream)
{
    const float* x      = (const float*)d_in[0];
    const float* qkv_w  = (const float*)d_in[1];
    const float* qkv_b  = (const float*)d_in[2];
    const float* out_w  = (const float*)d_in[3];
    const float* out_b  = (const float*)d_in[4];
    const float* gates  = (const float*)d_in[5];
    const float* imp    = (const float*)d_in[6];
    const float* thr    = (const float*)d_in[7];
    float* out = (float*)d_out;

    const size_t TSZ = (size_t)BH * SS * DD_;   // 4 Mi halfs per tensor
    f16* q16  = (f16*)d_ws;
    f16* k16  = q16 + TSZ;
    f16* v16  = k16 + TSZ;
    f16* vtb  = v16 + TSZ;
    f16* aout = vtb + TSZ;
    float* vmean = (float*)(aout + TSZ);        // BH*DD_ floats

    hipMemsetAsync(vmean, 0, (size_t)BH * DD_ * sizeof(float), stream);

    dim3 g1(NQKV/128, MROWS/128);   // 24 x 32
    qkv_gemm_kernel<<<g1, 256, 0, stream>>>(x, qkv_w, qkv_b, gates, imp, thr,
                                            q16, k16, v16);
    dim3 g2(SS/64, BH);             // 32 x 32
    vtrans_kernel<<<g2, 256, 0, stream>>>(v16, vtb, vmean);
    attn_kernel<<<g2, 256, 0, stream>>>(q16, k16, vtb, vmean, aout);
    dim3 g3(EE/128, MROWS/128);     // 8 x 32
    out_gemm_kernel<<<g3, 256, 0, stream>>>(aout, out_w, out_b, out);
}

// Round 3
// 232.761 us; speedup vs baseline: 6.9303x; 1.1599x over previous
//
#include <hip/hip_runtime.h>

#define BB 2
#define SS 2048
#define EE 1024
#define HH 16
#define DD_ 64
#define BH (BB*HH)
#define NQKV (3*EE)
#define MROWS (BB*SS)

typedef _Float16 f16;
typedef _Float16 f16x8 __attribute__((ext_vector_type(8)));
typedef _Float16 f16x4 __attribute__((ext_vector_type(4)));
typedef float f32x4 __attribute__((ext_vector_type(4)));

#define MFMA16(a,b,c) __builtin_amdgcn_mfma_f32_16x16x32_f16(a,b,c,0,0,0)
#define EXP2F(x) __builtin_amdgcn_exp2f(x)
#define LOG2E 1.44269504088896f

// ---------------------------------------------------------------------------
// fp32 -> f16 one-shot convert: x (4M), qkv_w (3M), out_w (1M) floats.
// ---------------------------------------------------------------------------
#define NX4  1048576   // x float4 count
#define NW14  786432   // qkv_w float4 count
#define NW24  262144   // out_w float4 count
__global__ __launch_bounds__(256) void cvt_kernel(
    const float* __restrict__ x, const float* __restrict__ w1,
    const float* __restrict__ w2, f16* __restrict__ x16,
    f16* __restrict__ w116, f16* __restrict__ w216)
{
    const int i = blockIdx.x * 256 + threadIdx.x;     // float4 index
    const float* src; f16* dst; int off;
    if (i < NX4)              { src = x;  dst = x16;  off = i; }
    else if (i < NX4 + NW14)  { src = w1; dst = w116; off = i - NX4; }
    else                      { src = w2; dst = w216; off = i - NX4 - NW14; }
    float4 v = ((const float4*)src)[off];
    f16x4 h = { (f16)v.x, (f16)v.y, (f16)v.z, (f16)v.w };
    *(f16x4*)(dst + 4*(size_t)off) = h;
}

// ---------------------------------------------------------------------------
// QKV GEMM, f16 MFMA, pure-f16 staging. Tile 128x128, BK=64, 4 waves.
// q output pre-scaled by log2(e) for base-2 softmax downstream.
// ---------------------------------------------------------------------------
__global__ __launch_bounds__(256) void qkv_gemm_kernel(
    const f16* __restrict__ x, const f16* __restrict__ w,
    const float* __restrict__ bias, const float* __restrict__ gates,
    const float* __restrict__ imp, const float* __restrict__ thr,
    f16* __restrict__ q16, f16* __restrict__ k16, f16* __restrict__ v16)
{
    __shared__ f16 As[128][72];
    __shared__ f16 Bs[128][72];
    const int tid  = threadIdx.x;
    const int wave = tid >> 6, lane = tid & 63;
    const int quad = lane >> 4, l15 = lane & 15;
    const int wm = wave & 1, wn = wave >> 1;
    const int m0 = blockIdx.y << 7, n0 = blockIdx.x << 7;

    f32x4 acc[4][4];
#pragma unroll
    for (int i = 0; i < 4; ++i)
#pragma unroll
        for (int j = 0; j < 4; ++j) acc[i][j] = (f32x4){0.f,0.f,0.f,0.f};

    for (int k0 = 0; k0 < EE; k0 += 64) {
        __syncthreads();
#pragma unroll
        for (int u = 0; u < 4; ++u) {
            const int f = tid + (u << 8);
            const int r = f >> 3, c = (f & 7) << 3;
            *(f16x8*)&As[r][c] = *(const f16x8*)(x + (size_t)(m0 + r)*EE + k0 + c);
            *(f16x8*)&Bs[r][c] = *(const f16x8*)(w + (size_t)(n0 + r)*EE + k0 + c);
        }
        __syncthreads();
#pragma unroll
        for (int ks = 0; ks < 2; ++ks) {
            f16x8 af[4], bf[4];
#pragma unroll
            for (int i = 0; i < 4; ++i)
                af[i] = *(const f16x8*)&As[wm*64 + i*16 + l15][ks*32 + quad*8];
#pragma unroll
            for (int j = 0; j < 4; ++j)
                bf[j] = *(const f16x8*)&Bs[wn*64 + j*16 + l15][ks*32 + quad*8];
#pragma unroll
            for (int i = 0; i < 4; ++i)
#pragma unroll
                for (int j = 0; j < 4; ++j)
                    acc[i][j] = MFMA16(af[i], bf[j], acc[i][j]);
        }
    }

    const int nb    = n0 + wn * 64;
    const int which = nb >> 10;
    const int h     = (nb & 1023) >> 6;
    const float gs   = 1.f / (1.f + __expf(-gates[h] * imp[h]));
    float scale = (gs > thr[0]) ? 1.f : 0.f;
    if (which == 0) scale *= LOG2E;          // base-2 softmax pre-scale on q
    f16* __restrict__ dst = (which == 0) ? q16 : ((which == 1) ? k16 : v16);
    float bv[4];
#pragma unroll
    for (int j = 0; j < 4; ++j) bv[j] = bias[nb + j*16 + l15];
#pragma unroll
    for (int i = 0; i < 4; ++i) {
#pragma unroll
        for (int reg = 0; reg < 4; ++reg) {
            const int m = m0 + wm*64 + i*16 + quad*4 + reg;
            const int b = m >> 11, s = m & (SS - 1);
            f16* rowp = dst + (((size_t)(b*HH + h))*SS + s)*DD_ + l15;
#pragma unroll
            for (int j = 0; j < 4; ++j)
                rowp[j*16] = (f16)((acc[i][j][reg] + bv[j]) * scale);
        }
    }
}

// ---------------------------------------------------------------------------
// v transpose [B,H,S,D] -> [B,H,D,S] f16, + vmean (fp32 atomic partials)
// ---------------------------------------------------------------------------
__global__ __launch_bounds__(256) void vtrans_kernel(
    const f16* __restrict__ v16, f16* __restrict__ vt, float* __restrict__ vmean)
{
    __shared__ f16 T[64][74];
    const int tid = threadIdx.x;
    const int bh = blockIdx.y, s0 = blockIdx.x << 6;
#pragma unroll
    for (int u = 0; u < 2; ++u) {
        const int f = tid + (u << 8);
        const int r = f >> 3, c = (f & 7) << 3;
        *(f16x8*)&T[r][c] = *(const f16x8*)(v16 + ((size_t)bh*SS + s0 + r)*DD_ + c);
    }
    __syncthreads();
    const int d = tid >> 2, ch = (tid & 3) << 4;
    union { f16 h[16]; f16x8 v8[2]; } t;
    float ps = 0.f;
#pragma unroll
    for (int u = 0; u < 16; ++u) { f16 val = T[ch + u][d]; t.h[u] = val; ps += (float)val; }
    f16* dp = vt + ((size_t)bh*DD_ + d)*SS + s0 + ch;
    *(f16x8*)(dp)     = t.v8[0];
    *(f16x8*)(dp + 8) = t.v8[1];
    ps += __shfl_xor(ps, 1, 64);
    ps += __shfl_xor(ps, 2, 64);
    if ((tid & 3) == 0) atomicAdd(vmean + bh*DD_ + d, ps * (1.f / SS));
}

// ---------------------------------------------------------------------------
// Flash attention, f16 MFMA, base-2 softmax. 512 thr = 8 waves = 128 q-rows
// per block. S^T = K*Q^T per wave (16 q-rows); P packed b64 into LDS; PV on
// V^T tiles.
// ---------------------------------------------------------------------------
__global__ __launch_bounds__(512) void attn_kernel(
    const f16* __restrict__ q16, const f16* __restrict__ k16,
    const f16* __restrict__ vt, const float* __restrict__ vmean,
    f16* __restrict__ aout)
{
    __shared__ f16 Ks[64][72];
    __shared__ f16 Vs[64][72];       // Vs[d][s]
    __shared__ f16 Ps[8][16][72];
    const int tid  = threadIdx.x;
    const int wave = tid >> 6, lane = tid & 63;
    const int quad = lane >> 4, l15 = lane & 15;
    const int bh = blockIdx.y, q0 = blockIdx.x << 7;
    const f16* qb = q16 + (size_t)bh * SS * DD_;
    const f16* kb = k16 + (size_t)bh * SS * DD_;
    const f16* vb = vt  + (size_t)bh * DD_ * SS;

    f16x8 qf[2];
#pragma unroll
    for (int ks = 0; ks < 2; ++ks)
        qf[ks] = *(const f16x8*)(qb + (size_t)(q0 + wave*16 + l15)*DD_ + ks*32 + quad*8);

    f32x4 accO[4];
#pragma unroll
    for (int dt = 0; dt < 4; ++dt) accO[dt] = (f32x4){0.f,0.f,0.f,0.f};
    float mold = -1.0e30f, lsum = 0.f;

    for (int kt = 0; kt < SS; kt += 64) {
        __syncthreads();
        {
            const int r = tid >> 3, c = (tid & 7) << 3;
            *(f16x8*)&Ks[r][c] = *(const f16x8*)(kb + (size_t)(kt + r)*DD_ + c);
            *(f16x8*)&Vs[r][c] = *(const f16x8*)(vb + (size_t)r*SS + kt + c);
        }
        __syncthreads();

        // S^T[key][qrow] in base-2 domain (q pre-scaled by log2 e)
        f32x4 accS[4];
#pragma unroll
        for (int mt = 0; mt < 4; ++mt) accS[mt] = (f32x4){0.f,0.f,0.f,0.f};
#pragma unroll
        for (int ks = 0; ks < 2; ++ks)
#pragma unroll
            for (int mt = 0; mt < 4; ++mt) {
                f16x8 kf = *(const f16x8*)&Ks[mt*16 + l15][ks*32 + quad*8];
                accS[mt] = MFMA16(kf, qf[ks], accS[mt]);
            }

        float mx = -1.0e30f;
#pragma unroll
        for (int mt = 0; mt < 4; ++mt)
#pragma unroll
            for (int reg = 0; reg < 4; ++reg) mx = fmaxf(mx, accS[mt][reg]);
        mx = fmaxf(mx, __shfl_xor(mx, 16, 64));
        mx = fmaxf(mx, __shfl_xor(mx, 32, 64));
        const float mnew = fmaxf(mold, mx);
        float sum = 0.f;
#pragma unroll
        for (int mt = 0; mt < 4; ++mt)
#pragma unroll
            for (int reg = 0; reg < 4; ++reg) {
                float p = EXP2F(accS[mt][reg] - mnew);
                accS[mt][reg] = p; sum += p;
            }
        sum += __shfl_xor(sum, 16, 64);
        sum += __shfl_xor(sum, 32, 64);
        const float alpha = EXP2F(mold - mnew);
        lsum = lsum * alpha + sum;
        mold = mnew;
#pragma unroll
        for (int reg = 0; reg < 4; ++reg) {
            const float ar = __shfl(alpha, quad*4 + reg, 64);
#pragma unroll
            for (int dt = 0; dt < 4; ++dt) accO[dt][reg] *= ar;
        }
        // P^T -> Ps, packed 8B stores
#pragma unroll
        for (int mt = 0; mt < 4; ++mt) {
            f16x4 ph = { (f16)accS[mt][0], (f16)accS[mt][1],
                         (f16)accS[mt][2], (f16)accS[mt][3] };
            *(f16x4*)&Ps[wave][l15][mt*16 + quad*4] = ph;
        }
        f16x8 af[2];
#pragma unroll
        for (int ks = 0; ks < 2; ++ks)
            af[ks] = *(const f16x8*)&Ps[wave][l15][ks*32 + quad*8];
#pragma unroll
        for (int ks = 0; ks < 2; ++ks)
#pragma unroll
            for (int dt = 0; dt < 4; ++dt) {
                f16x8 vf = *(const f16x8*)&Vs[dt*16 + l15][ks*32 + quad*8];
                accO[dt] = MFMA16(af[ks], vf, accO[dt]);
            }
    }

    const int b = bh >> 4, h = bh & (HH - 1);
#pragma unroll
    for (int reg = 0; reg < 4; ++reg) {
        const float lf = __shfl(lsum, quad*4 + reg, 64);
        const float inv = 1.f / lf;
        const int s = q0 + wave*16 + quad*4 + reg;
#pragma unroll
        for (int dt = 0; dt < 4; ++dt) {
            float val = accO[dt][reg] * inv + vmean[bh*DD_ + dt*16 + l15];
            aout[((size_t)(b*SS + s))*EE + h*DD_ + dt*16 + l15] = (f16)val;
        }
    }
}

// ---------------------------------------------------------------------------
// Output GEMM, f16 MFMA, pure-f16 staging: y[m,n] = sum_k a[m,k]*w[n,k] + b[n]
// ---------------------------------------------------------------------------
__global__ __launch_bounds__(256) void out_gemm_kernel(
    const f16* __restrict__ a, const f16* __restrict__ w,
    const float* __restrict__ bias, float* __restrict__ y)
{
    __shared__ f16 As[128][72];
    __shared__ f16 Bs[128][72];
    const int tid  = threadIdx.x;
    const int wave = tid >> 6, lane = tid & 63;
    const int quad = lane >> 4, l15 = lane & 15;
    const int wm = wave & 1, wn = wave >> 1;
    const int m0 = blockIdx.y << 7, n0 = blockIdx.x << 7;

    f32x4 acc[4][4];
#pragma unroll
    for (int i = 0; i < 4; ++i)
#pragma unroll
        for (int j = 0; j < 4; ++j) acc[i][j] = (f32x4){0.f,0.f,0.f,0.f};

    for (int k0 = 0; k0 < EE; k0 += 64) {
        __syncthreads();
#pragma unroll
        for (int u = 0; u < 4; ++u) {
            const int f = tid + (u << 8);
            const int r = f >> 3, c = (f & 7) << 3;
            *(f16x8*)&As[r][c] = *(const f16x8*)(a + (size_t)(m0 + r)*EE + k0 + c);
            *(f16x8*)&Bs[r][c] = *(const f16x8*)(w + (size_t)(n0 + r)*EE + k0 + c);
        }
        __syncthreads();
#pragma unroll
        for (int ks = 0; ks < 2; ++ks) {
            f16x8 af[4], bf[4];
#pragma unroll
            for (int i = 0; i < 4; ++i)
                af[i] = *(const f16x8*)&As[wm*64 + i*16 + l15][ks*32 + quad*8];
#pragma unroll
            for (int j = 0; j < 4; ++j)
                bf[j] = *(const f16x8*)&Bs[wn*64 + j*16 + l15][ks*32 + quad*8];
#pragma unroll
            for (int i = 0; i < 4; ++i)
#pragma unroll
                for (int j = 0; j < 4; ++j)
                    acc[i][j] = MFMA16(af[i], bf[j], acc[i][j]);
        }
    }

    float bv[4];
#pragma unroll
    for (int j = 0; j < 4; ++j) bv[j] = bias[n0 + wn*64 + j*16 + l15];
#pragma unroll
    for (int i = 0; i < 4; ++i) {
#pragma unroll
        for (int reg = 0; reg < 4; ++reg) {
            const int m = m0 + wm*64 + i*16 + quad*4 + reg;
#pragma unroll
            for (int j = 0; j < 4; ++j)
                y[(size_t)m*EE + n0 + wn*64 + j*16 + l15] = acc[i][j][reg] + bv[j];
        }
    }
}

// ---------------------------------------------------------------------------
extern "C" void kernel_launch(void* const* d_in, const int* in_sizes, int n_in,
                              void* d_out, int out_size, void* d_ws, size_t ws_size,
                              hipStream_t stream)
{
    const float* x      = (const float*)d_in[0];
    const float* qkv_w  = (const float*)d_in[1];
    const float* qkv_b  = (const float*)d_in[2];
    const float* out_w  = (const float*)d_in[3];
    const float* out_b  = (const float*)d_in[4];
    const float* gates  = (const float*)d_in[5];
    const float* imp    = (const float*)d_in[6];
    const float* thr    = (const float*)d_in[7];
    float* out = (float*)d_out;

    const size_t TSZ = (size_t)BH * SS * DD_;   // 4 Mi halfs
    f16* x16  = (f16*)d_ws;                     // 4 Mi
    f16* w116 = x16 + (size_t)MROWS * EE;       // 3 Mi
    f16* w216 = w116 + (size_t)NQKV * EE;       // 1 Mi
    f16* q16  = w216 + (size_t)EE * EE;
    f16* k16  = q16 + TSZ;
    f16* v16  = k16 + TSZ;
    f16* vtb  = v16 + TSZ;
    f16* aout = vtb + TSZ;
    float* vmean = (float*)(aout + TSZ);        // BH*DD_ floats

    hipMemsetAsync(vmean, 0, (size_t)BH * DD_ * sizeof(float), stream);

    cvt_kernel<<<(NX4 + NW14 + NW24) / 256, 256, 0, stream>>>(
        x, qkv_w, out_w, x16, w116, w216);

    dim3 g1(NQKV/128, MROWS/128);   // 24 x 32
    qkv_gemm_kernel<<<g1, 256, 0, stream>>>(x16, w116, qkv_b, gates, imp, thr,
                                            q16, k16, v16);
    dim3 g2(SS/64, BH);             // 32 x 32
    vtrans_kernel<<<g2, 256, 0, stream>>>(v16, vtb, vmean);
    dim3 g2a(SS/128, BH);           // 16 x 32
    attn_kernel<<<g2a, 512, 0, stream>>>(q16, k16, vtb, vmean, aout);
    dim3 g3(EE/128, MROWS/128);     // 8 x 32
    out_gemm_kernel<<<g3, 256, 0, stream>>>(aout, out_w ? w216 : w216, out_b, out);
}

// Round 4
// 231.789 us; speedup vs baseline: 6.9594x; 1.0042x over previous
//
#include <hip/hip_runtime.h>

#define BB 2
#define SS 2048
#define EE 1024
#define HH 16
#define DD_ 64
#define BH (BB*HH)
#define NQKV (3*EE)
#define MROWS (BB*SS)

typedef _Float16 f16;
typedef _Float16 f16x8 __attribute__((ext_vector_type(8)));
typedef _Float16 f16x4 __attribute__((ext_vector_type(4)));
typedef float f32x4 __attribute__((ext_vector_type(4)));
typedef float f32x16 __attribute__((ext_vector_type(16)));

#define MFMA16(a,b,c) __builtin_amdgcn_mfma_f32_16x16x32_f16(a,b,c,0,0,0)
#define MFMA32(a,b,c) __builtin_amdgcn_mfma_f32_32x32x16_f16(a,b,c,0,0,0)
#define EXP2F(x) __builtin_amdgcn_exp2f(x)
#define LOG2E 1.44269504088896f

__device__ __forceinline__ void gload16(const void* g, void* l) {
    __builtin_amdgcn_global_load_lds(
        (const __attribute__((address_space(1))) void*)g,
        (__attribute__((address_space(3))) void*)l, 16, 0, 0);
}

// ---------------------------------------------------------------------------
// fp32 -> f16 one-shot convert: x (4M), qkv_w (3M), out_w (1M) floats.
// ---------------------------------------------------------------------------
#define NX4  1048576
#define NW14  786432
#define NW24  262144
__global__ __launch_bounds__(256) void cvt_kernel(
    const float* __restrict__ x, const float* __restrict__ w1,
    const float* __restrict__ w2, f16* __restrict__ x16,
    f16* __restrict__ w116, f16* __restrict__ w216)
{
    const int i = blockIdx.x * 256 + threadIdx.x;
    const float* src; f16* dst; int off;
    if (i < NX4)              { src = x;  dst = x16;  off = i; }
    else if (i < NX4 + NW14)  { src = w1; dst = w116; off = i - NX4; }
    else                      { src = w2; dst = w216; off = i - NX4 - NW14; }
    float4 v = ((const float4*)src)[off];
    f16x4 h = { (f16)v.x, (f16)v.y, (f16)v.z, (f16)v.w };
    *(f16x4*)(dst + 4*(size_t)off) = h;
}

// ---------------------------------------------------------------------------
// QKV GEMM, f16 MFMA 16x16x32, 128x128 tile, BK=64, 4 waves.
// global_load_lds staging with XOR-swizzled source (conflict-free LDS).
// q pre-scaled by log2(e).
// ---------------------------------------------------------------------------
__global__ __launch_bounds__(256) void qkv_gemm_kernel(
    const f16* __restrict__ x, const f16* __restrict__ w,
    const float* __restrict__ bias, const float* __restrict__ gates,
    const float* __restrict__ imp, const float* __restrict__ thr,
    f16* __restrict__ q16, f16* __restrict__ k16, f16* __restrict__ v16)
{
    __shared__ f16 As[128*64];
    __shared__ f16 Bs[128*64];
    const int tid  = threadIdx.x;
    const int wave = tid >> 6, lane = tid & 63;
    const int quad = lane >> 4, l15 = lane & 15;
    const int wm = wave & 1, wn = wave >> 1;
    const int m0 = blockIdx.y << 7, n0 = blockIdx.x << 7;

    f32x4 acc[4][4];
#pragma unroll
    for (int i = 0; i < 4; ++i)
#pragma unroll
        for (int j = 0; j < 4; ++j) acc[i][j] = (f32x4){0.f,0.f,0.f,0.f};

    for (int k0 = 0; k0 < EE; k0 += 64) {
        __syncthreads();
#pragma unroll
        for (int u = 0; u < 4; ++u) {
            const int s = tid + (u << 8);            // slot 0..1023
            const int r = s >> 3;
            const int sc = ((s & 7) ^ (r & 7)) << 3; // swizzled source chunk
            gload16(x + (size_t)(m0 + r)*EE + k0 + sc, &As[s << 3]);
            gload16(w + (size_t)(n0 + r)*EE + k0 + sc, &Bs[s << 3]);
        }
        __syncthreads();
#pragma unroll
        for (int ks = 0; ks < 2; ++ks) {
            f16x8 af[4], bf[4];
#pragma unroll
            for (int i = 0; i < 4; ++i) {
                const int r = wm*64 + i*16 + l15;
                af[i] = *(const f16x8*)&As[(r << 6) + ((((ks<<2)+quad) ^ (l15 & 7)) << 3)];
            }
#pragma unroll
            for (int j = 0; j < 4; ++j) {
                const int r = wn*64 + j*16 + l15;
                bf[j] = *(const f16x8*)&Bs[(r << 6) + ((((ks<<2)+quad) ^ (l15 & 7)) << 3)];
            }
#pragma unroll
            for (int i = 0; i < 4; ++i)
#pragma unroll
                for (int j = 0; j < 4; ++j)
                    acc[i][j] = MFMA16(af[i], bf[j], acc[i][j]);
        }
    }

    const int nb    = n0 + wn * 64;
    const int which = nb >> 10;
    const int h     = (nb & 1023) >> 6;
    const float gs   = 1.f / (1.f + __expf(-gates[h] * imp[h]));
    float scale = (gs > thr[0]) ? 1.f : 0.f;
    if (which == 0) scale *= LOG2E;
    f16* __restrict__ dst = (which == 0) ? q16 : ((which == 1) ? k16 : v16);
    float bv[4];
#pragma unroll
    for (int j = 0; j < 4; ++j) bv[j] = bias[nb + j*16 + l15];
#pragma unroll
    for (int i = 0; i < 4; ++i) {
#pragma unroll
        for (int reg = 0; reg < 4; ++reg) {
            const int m = m0 + wm*64 + i*16 + quad*4 + reg;
            const int b = m >> 11, s = m & (SS - 1);
            f16* rowp = dst + (((size_t)(b*HH + h))*SS + s)*DD_ + l15;
#pragma unroll
            for (int j = 0; j < 4; ++j)
                rowp[j*16] = (f16)((acc[i][j][reg] + bv[j]) * scale);
        }
    }
}

// ---------------------------------------------------------------------------
// v transpose [B,H,S,D] -> [B,H,D,S] f16, + vmean (fp32 atomic partials)
// ---------------------------------------------------------------------------
__global__ __launch_bounds__(256) void vtrans_kernel(
    const f16* __restrict__ v16, f16* __restrict__ vt, float* __restrict__ vmean)
{
    __shared__ f16 T[64][74];
    const int tid = threadIdx.x;
    const int bh = blockIdx.y, s0 = blockIdx.x << 6;
#pragma unroll
    for (int u = 0; u < 2; ++u) {
        const int f = tid + (u << 8);
        const int r = f >> 3, c = (f & 7) << 3;
        *(f16x8*)&T[r][c] = *(const f16x8*)(v16 + ((size_t)bh*SS + s0 + r)*DD_ + c);
    }
    __syncthreads();
    const int d = tid >> 2, ch = (tid & 3) << 4;
    union { f16 h[16]; f16x8 v8[2]; } t;
    float ps = 0.f;
#pragma unroll
    for (int u = 0; u < 16; ++u) { f16 val = T[ch + u][d]; t.h[u] = val; ps += (float)val; }
    f16* dp = vt + ((size_t)bh*DD_ + d)*SS + s0 + ch;
    *(f16x8*)(dp)     = t.v8[0];
    *(f16x8*)(dp + 8) = t.v8[1];
    ps += __shfl_xor(ps, 1, 64);
    ps += __shfl_xor(ps, 2, 64);
    if ((tid & 3) == 0) atomicAdd(vmean + bh*DD_ + d, ps * (1.f / SS));
}

// ---------------------------------------------------------------------------
// Flash attention, 32x32x16 MFMA, base-2 softmax, XOR-swizzled LDS,
// global_load_lds staging. 512 thr = 8 waves x 32 q-rows = 256 q-rows/block.
// S^T = K*Q^T (lane owns q-row = lane&31); P -> LDS (swizzled) -> PV on V^T.
// ---------------------------------------------------------------------------
__global__ __launch_bounds__(512, 4) void attn_kernel(
    const f16* __restrict__ q16, const f16* __restrict__ k16,
    const f16* __restrict__ vt, const float* __restrict__ vmean,
    f16* __restrict__ aout)
{
    __shared__ f16 Ks[64*64];          // [key][d], swizzled chunks
    __shared__ f16 Vs[64*64];          // [d][key], swizzled chunks
    __shared__ f16 Ps[8][32*64];       // per-wave [qrow][key], swizzled
    const int tid  = threadIdx.x;
    const int wave = tid >> 6, lane = tid & 63;
    const int l31 = lane & 31, hi = lane >> 5, l7 = lane & 7;
    const int bh = blockIdx.y, q0 = blockIdx.x << 8;
    const f16* qb = q16 + (size_t)bh * SS * DD_;
    const f16* kb = k16 + (size_t)bh * SS * DD_;
    const f16* vb = vt  + (size_t)bh * DD_ * SS;

    // Q fragments (B-operand): B[k=ks*16+hi*8+j][n=qrow=l31]
    f16x8 qf[4];
#pragma unroll
    for (int ks = 0; ks < 4; ++ks)
        qf[ks] = *(const f16x8*)(qb + (size_t)(q0 + wave*32 + l31)*DD_ + ks*16 + hi*8);

    f32x16 accO[2];
#pragma unroll
    for (int dt = 0; dt < 2; ++dt)
#pragma unroll
        for (int r = 0; r < 16; ++r) accO[dt][r] = 0.f;
    float mold = -1.0e30f, lsum = 0.f;

    // staging slot for this thread (one 16B chunk of K and of V per iter)
    const int srow = tid >> 3;                        // 0..63
    const int schk = ((tid & 7) ^ (srow & 7)) << 3;   // swizzled source chunk

    for (int kt = 0; kt < SS; kt += 64) {
        __syncthreads();
        gload16(kb + (size_t)(kt + srow)*DD_ + schk, &Ks[tid << 3]);
        gload16(vb + (size_t)srow*SS + kt + schk,    &Vs[tid << 3]);
        __syncthreads();

        // S^T[key][qrow]: A = K tile rows, B = Q^T
        f32x16 accS[2];
#pragma unroll
        for (int mt = 0; mt < 2; ++mt)
#pragma unroll
            for (int r = 0; r < 16; ++r) accS[mt][r] = 0.f;
#pragma unroll
        for (int ks = 0; ks < 4; ++ks)
#pragma unroll
            for (int mt = 0; mt < 2; ++mt) {
                const int r = mt*32 + l31;
                f16x8 kf = *(const f16x8*)&Ks[(r << 6) + ((((ks<<1)+hi) ^ l7) << 3)];
                accS[mt] = MFMA32(kf, qf[ks], accS[mt]);
            }

        // online softmax for q-row l31 (this lane holds 32 of its 64 scores)
        float mx = -1.0e30f;
#pragma unroll
        for (int mt = 0; mt < 2; ++mt)
#pragma unroll
            for (int r = 0; r < 16; ++r) mx = fmaxf(mx, accS[mt][r]);
        mx = fmaxf(mx, __shfl_xor(mx, 32, 64));
        const float mnew = fmaxf(mold, mx);
        float sum = 0.f;
#pragma unroll
        for (int mt = 0; mt < 2; ++mt)
#pragma unroll
            for (int r = 0; r < 16; ++r) {
                float p = EXP2F(accS[mt][r] - mnew);
                accS[mt][r] = p; sum += p;
            }
        sum += __shfl_xor(sum, 32, 64);
        const float alpha = EXP2F(mold - mnew);
        lsum = lsum * alpha + sum;
        mold = mnew;
        // rescale accO: row(reg) = (reg&3)+8*(reg>>2)+4*hi; alpha lives at lane=row
#pragma unroll
        for (int reg = 0; reg < 16; ++reg) {
            const float ar = __shfl(alpha, (reg & 3) + 8*(reg >> 2) + 4*hi, 64);
            accO[0][reg] *= ar;
            accO[1][reg] *= ar;
        }
        // P -> Ps[qrow][key] (swizzled): keys mt*32+8g+4hi+(0..3) from regs g*4..+3
#pragma unroll
        for (int mt = 0; mt < 2; ++mt)
#pragma unroll
            for (int g = 0; g < 4; ++g) {
                f16x4 ph = { (f16)accS[mt][g*4+0], (f16)accS[mt][g*4+1],
                             (f16)accS[mt][g*4+2], (f16)accS[mt][g*4+3] };
                *(f16x4*)&Ps[wave][(l31 << 6) + ((((mt<<2)+g) ^ l7) << 3) + (hi << 2)] = ph;
            }
        // PV: A = P[qrow][key], B = V^T[d][key]
        f16x8 af[4];
#pragma unroll
        for (int ks = 0; ks < 4; ++ks)
            af[ks] = *(const f16x8*)&Ps[wave][(l31 << 6) + ((((ks<<1)+hi) ^ l7) << 3)];
#pragma unroll
        for (int ks = 0; ks < 4; ++ks)
#pragma unroll
            for (int dt = 0; dt < 2; ++dt) {
                const int r = dt*32 + l31;
                f16x8 vf = *(const f16x8*)&Vs[(r << 6) + ((((ks<<1)+hi) ^ l7) << 3)];
                accO[dt] = MFMA32(af[ks], vf, accO[dt]);
            }
    }

    const int b = bh >> 4, h = bh & (HH - 1);
    const float vm0 = vmean[bh*DD_ + l31];
    const float vm1 = vmean[bh*DD_ + 32 + l31];
#pragma unroll
    for (int reg = 0; reg < 16; ++reg) {
        const int qr = (reg & 3) + 8*(reg >> 2) + 4*hi;
        const float lf = __shfl(lsum, qr, 64);
        const float inv = 1.f / lf;
        const int s = q0 + wave*32 + qr;
        f16* op = aout + ((size_t)(b*SS + s))*EE + h*DD_;
        op[l31]      = (f16)(accO[0][reg] * inv + vm0);
        op[32 + l31] = (f16)(accO[1][reg] * inv + vm1);
    }
}

// ---------------------------------------------------------------------------
// Output GEMM, f16 MFMA, global_load_lds + swizzle: y = a@w^T + b (fp32 out)
// ---------------------------------------------------------------------------
__global__ __launch_bounds__(256) void out_gemm_kernel(
    const f16* __restrict__ a, const f16* __restrict__ w,
    const float* __restrict__ bias, float* __restrict__ y)
{
    __shared__ f16 As[128*64];
    __shared__ f16 Bs[128*64];
    const int tid  = threadIdx.x;
    const int wave = tid >> 6, lane = tid & 63;
    const int quad = lane >> 4, l15 = lane & 15;
    const int wm = wave & 1, wn = wave >> 1;
    const int m0 = blockIdx.y << 7, n0 = blockIdx.x << 7;

    f32x4 acc[4][4];
#pragma unroll
    for (int i = 0; i < 4; ++i)
#pragma unroll
        for (int j = 0; j < 4; ++j) acc[i][j] = (f32x4){0.f,0.f,0.f,0.f};

    for (int k0 = 0; k0 < EE; k0 += 64) {
        __syncthreads();
#pragma unroll
        for (int u = 0; u < 4; ++u) {
            const int s = tid + (u << 8);
            const int r = s >> 3;
            const int sc = ((s & 7) ^ (r & 7)) << 3;
            gload16(a + (size_t)(m0 + r)*EE + k0 + sc, &As[s << 3]);
            gload16(w + (size_t)(n0 + r)*EE + k0 + sc, &Bs[s << 3]);
        }
        __syncthreads();
#pragma unroll
        for (int ks = 0; ks < 2; ++ks) {
            f16x8 af[4], bf[4];
#pragma unroll
            for (int i = 0; i < 4; ++i) {
                const int r = wm*64 + i*16 + l15;
                af[i] = *(const f16x8*)&As[(r << 6) + ((((ks<<2)+quad) ^ (l15 & 7)) << 3)];
            }
#pragma unroll
            for (int j = 0; j < 4; ++j) {
                const int r = wn*64 + j*16 + l15;
                bf[j] = *(const f16x8*)&Bs[(r << 6) + ((((ks<<2)+quad) ^ (l15 & 7)) << 3)];
            }
#pragma unroll
            for (int i = 0; i < 4; ++i)
#pragma unroll
                for (int j = 0; j < 4; ++j)
                    acc[i][j] = MFMA16(af[i], bf[j], acc[i][j]);
        }
    }

    float bv[4];
#pragma unroll
    for (int j = 0; j < 4; ++j) bv[j] = bias[n0 + wn*64 + j*16 + l15];
#pragma unroll
    for (int i = 0; i < 4; ++i) {
#pragma unroll
        for (int reg = 0; reg < 4; ++reg) {
            const int m = m0 + wm*64 + i*16 + quad*4 + reg;
#pragma unroll
            for (int j = 0; j < 4; ++j)
                y[(size_t)m*EE + n0 + wn*64 + j*16 + l15] = acc[i][j][reg] + bv[j];
        }
    }
}

// ---------------------------------------------------------------------------
extern "C" void kernel_launch(void* const* d_in, const int* in_sizes, int n_in,
                              void* d_out, int out_size, void* d_ws, size_t ws_size,
                              hipStream_t stream)
{
    const float* x      = (const float*)d_in[0];
    const float* qkv_w  = (const float*)d_in[1];
    const float* qkv_b  = (const float*)d_in[2];
    const float* out_w  = (const float*)d_in[3];
    const float* out_b  = (const float*)d_in[4];
    const float* gates  = (const float*)d_in[5];
    const float* imp    = (const float*)d_in[6];
    const float* thr    = (const float*)d_in[7];
    float* out = (float*)d_out;

    const size_t TSZ = (size_t)BH * SS * DD_;
    f16* x16  = (f16*)d_ws;
    f16* w116 = x16 + (size_t)MROWS * EE;
    f16* w216 = w116 + (size_t)NQKV * EE;
    f16* q16  = w216 + (size_t)EE * EE;
    f16* k16  = q16 + TSZ;
    f16* v16  = k16 + TSZ;
    f16* vtb  = v16 + TSZ;
    f16* aout = vtb + TSZ;
    float* vmean = (float*)(aout + TSZ);

    hipMemsetAsync(vmean, 0, (size_t)BH * DD_ * sizeof(float), stream);

    cvt_kernel<<<(NX4 + NW14 + NW24) / 256, 256, 0, stream>>>(
        x, qkv_w, out_w, x16, w116, w216);

    dim3 g1(NQKV/128, MROWS/128);   // 24 x 32
    qkv_gemm_kernel<<<g1, 256, 0, stream>>>(x16, w116, qkv_b, gates, imp, thr,
                                            q16, k16, v16);
    dim3 g2(SS/64, BH);             // 32 x 32
    vtrans_kernel<<<g2, 256, 0, stream>>>(v16, vtb, vmean);
    dim3 g2a(SS/256, BH);           // 8 x 32
    attn_kernel<<<g2a, 512, 0, stream>>>(q16, k16, vtb, vmean, aout);
    dim3 g3(EE/128, MROWS/128);     // 8 x 32
    out_gemm_kernel<<<g3, 256, 0, stream>>>(aout, w216, out_b, out);
}